// Round 8
// baseline (340.468 us; speedup 1.0000x reference)
//
#include <hip/hip_runtime.h>

// GatedRecurrentCell: pa/pi = x@W^T + b (fp16 MFMA) with gates FUSED into the
// GEMM epilogue; (a,c) stored fp16; chunked linear scan (64 chunks x 32 steps).
// Shapes: B=8 S=2048 D=512 I=2048. M=B*S=16384, N2=2*I=4096, K=D=512.
// R8 = R6 (last passing, 161us gemm) + XCD-aware bijective block remap (T1).
// Theory: staging traffic (256KB/block x 4096 blocks = 1.07GB) over 161us =
// 6.7 TB/s == the memory-system ceiling; concurrent-block working set ~26MB/XCD
// >> 4MB L2 -> L2 thrash -> fabric-bound. Remap vid=(orig&7)*512+(orig>>3)
// gives each XCD 16 M-rows x 32 N-blocks: A-panel L2-reused 32x, B (4MB wh)
// L2-resident per XCD. R7's barrier-free DMA experiment failed correctness
// (vmcnt->ds_read without barrier is unproven HW ground) and is reverted.
// ws: [0,16Mi) x_f16 | [16,20Mi) W_f16 | [20Mi,+128Mi) AC f16 | +8Mi agg | +4Mi carry

#define LOG2_3 1.5849625007211562f

typedef _Float16 f16x8 __attribute__((ext_vector_type(8)));
typedef _Float16 f16x4 __attribute__((ext_vector_type(4)));
typedef _Float16 f16x2 __attribute__((ext_vector_type(2)));
typedef float f32x4 __attribute__((ext_vector_type(4)));

__device__ __forceinline__ float sigmoid_fast(float v) {
  return __fdividef(1.0f, 1.0f + __expf(-v));
}

__device__ __forceinline__ void async_copy16(void* lds, const void* gp) {
  __builtin_amdgcn_global_load_lds((__attribute__((address_space(1))) void*)gp,
                                   (__attribute__((address_space(3))) void*)lds,
                                   16, 0, 0);
}

// x -> xh (plain). Wa/Wi -> wh with row interleave: wh row 2i = Wa_i, 2i+1 = Wi_i.
__global__ __launch_bounds__(256) void cvt_all(const float* __restrict__ x,
                                               const float* __restrict__ Wa,
                                               const float* __restrict__ Wi,
                                               _Float16* __restrict__ xh,
                                               _Float16* __restrict__ wh) {
  int idx = blockIdx.x * 256 + threadIdx.x;
  const float* src;
  _Float16* dst;
  int off, doff;
  if (idx < 2097152) {
    src = x; dst = xh; off = idx; doff = idx;
  } else if (idx < 2097152 + 262144) {
    src = Wa; dst = wh; off = idx - 2097152;
    doff = off + ((off >> 7) << 7);          // (2i)*128 + k4
  } else {
    src = Wi; dst = wh; off = idx - 2359296;
    doff = off + ((off >> 7) << 7) + 128;    // (2i+1)*128 + k4
  }
  float4 v = ((const float4*)src)[off];
  f16x4 h;
  h[0] = (_Float16)v.x;
  h[1] = (_Float16)v.y;
  h[2] = (_Float16)v.z;
  h[3] = (_Float16)v.w;
  ((f16x4*)dst)[doff] = h;
}

__device__ __forceinline__ void gate_ac(float pa, float pi, float alpha, float& a, float& c) {
  float rg = sigmoid_fast(pa);
  a = alpha * exp2f(-LOG2_3 * rg);
  float ig = sigmoid_fast(pi);
  float m = fmaxf(1.0f - a * a, 1e-8f);
  c = (m * __frsqrt_rn(m)) * (ig * pi);  // sqrt(m) = m * rsqrt(m)
}

// GEMM 128x128 tile + fused gate epilogue.
// AC[m][2i..2i+1] = (a,c) fp16. agg[(b*64+ch)][i] = (A,H) over 32-step chunk.
// Block remap (T1): orig = y*32+x (x fastest in dispatch); vid = (orig&7)*512
// + (orig>>3); by=vid>>5, bx=vid&31. XCD c (== orig&7 heuristic) owns
// by in [c*16,(c+1)*16), all bx -> A-panel reused 32x in-L2, B L2-resident.
// LDS: 2 K-buffers {As 4096 | Bs 4096} f16; epilogue reuses smem[0,8704).
// K-loop (minimum 2-phase): STAGE(nxt) -> ds_read(cur)+MFMA -> __syncthreads.
// Swizzle: 16B slot s at row r holds logical slot s ^ ((r>>1)&3); pre-swizzled
// global source (LDS dest linear for global_load_lds), reads apply same XOR.
__global__ __launch_bounds__(256) void gemm_gate(const _Float16* __restrict__ Ah,
                                                 const _Float16* __restrict__ Wh,
                                                 const float* __restrict__ ba,
                                                 const float* __restrict__ bi,
                                                 const float* __restrict__ gate,
                                                 _Float16* __restrict__ AC,
                                                 float2* __restrict__ agg) {
  constexpr int K = 512;
  constexpr int N2 = 4096;
  __shared__ __align__(16) _Float16 smem[16384];  // 32 KiB: 2 x (As 4096 | Bs 4096)
  __shared__ float pAs[8 * 65];                   // partials, padded stride 65
  __shared__ float pHs[8 * 65];
  const int t = threadIdx.x;
  // XCD-aware bijective remap (nwg=4096, 4096%8==0)
  const int orig = blockIdx.y * 32 + blockIdx.x;
  const int vid = (orig & 7) * 512 + (orig >> 3);
  const int bx = vid & 31;
  const int by = vid >> 5;
  const int mBase = by * 128;
  const int nBase = bx * 128;
  const int r = t >> 2;                      // staged row (0..63; +64 for 2nd half)
  const int p = t & 3;                       // physical 16B slot within row
  const int lsw = p ^ ((r >> 1) & 3);        // logical slot to fetch for this dest
  const _Float16* gA0 = Ah + (size_t)(mBase + r) * K + lsw * 8;
  const _Float16* gB0 = Wh + (size_t)(nBase + r) * K + lsw * 8;
  const int ldst = r * 32 + p * 8;           // f16 idx; byte off == t*16 (linear)

  const int lane = t & 63;
  const int wave = t >> 6;
  const int wm = (wave & 1) * 64;
  const int wn = (wave >> 1) * 64;
  const int lrow = lane & 15;
  const int quad = lane >> 4;
  const int xq = quad ^ ((lrow >> 1) & 3);   // read-side swizzle

  f32x4 acc[4][4];
#pragma unroll
  for (int i = 0; i < 4; ++i)
#pragma unroll
    for (int j = 0; j < 4; ++j)
      acc[i][j] = (f32x4)0.0f;

  _Float16* b0 = smem;
  _Float16* b1 = smem + 8192;

  auto STAGE = [&](int tt, _Float16* bb) {
    const int ko = tt * 32;
    async_copy16(bb + ldst, gA0 + ko);
    async_copy16(bb + 2048 + ldst, gA0 + (size_t)64 * K + ko);
    async_copy16(bb + 4096 + ldst, gB0 + ko);
    async_copy16(bb + 6144 + ldst, gB0 + (size_t)64 * K + ko);
  };

  STAGE(0, b0);
  __syncthreads();

#pragma unroll
  for (int kt = 0; kt < 16; ++kt) {
    _Float16* cur = (kt & 1) ? b1 : b0;
    _Float16* nxt = (kt & 1) ? b0 : b1;
    if (kt < 15) STAGE(kt + 1, nxt);  // issue BEFORE compute; lands by next barrier
    f16x8 af[4], bf[4];
#pragma unroll
    for (int i = 0; i < 4; ++i)
      af[i] = *(const f16x8*)(cur + (wm + i * 16 + lrow) * 32 + xq * 8);
#pragma unroll
    for (int j = 0; j < 4; ++j)
      bf[j] = *(const f16x8*)(cur + 4096 + (wn + j * 16 + lrow) * 32 + xq * 8);
#pragma unroll
    for (int i = 0; i < 4; ++i)
#pragma unroll
      for (int j = 0; j < 4; ++j)
        acc[i][j] = __builtin_amdgcn_mfma_f32_16x16x32_f16(af[i], bf[j], acc[i][j], 0, 0, 0);
    // single barrier/K-step: drains stage (vmcnt) + my reads (lgkm), publishes nxt
    __syncthreads();
  }

  // bias: col n even -> ba[n/2] (pa), odd -> bi[n/2] (pi)
  float bias[4];
#pragma unroll
  for (int j = 0; j < 4; ++j) {
    const int n = nBase + wn + j * 16 + lrow;
    bias[j] = (n & 1) ? bi[n >> 1] : ba[n >> 1];
  }

  // gate-phase thread roles: col = i-lane 0..63, q = s-quarter (16 rows each)
  const int col = t & 63;
  const int q = t >> 6;
  const float alpha = sigmoid_fast(gate[(nBase >> 1) + col]);
  const int b = by >> 4;  // 16 m-tiles per batch

  // 2 rounds of 64 m-rows: stage C+bias -> LDS, compute a,c, store AC, local scan.
  // C/D layout: col = lane&15, row = quad*4 + reg (m89-verified)
#pragma unroll
  for (int h = 0; h < 2; ++h) {
    if (wm == h * 64) {
#pragma unroll
      for (int i = 0; i < 4; ++i)
#pragma unroll
        for (int j = 0; j < 4; ++j)
#pragma unroll
          for (int rr = 0; rr < 4; ++rr)
            smem[(i * 16 + quad * 4 + rr) * 136 + wn + j * 16 + lrow] =
                (_Float16)(acc[i][j][rr] + bias[j]);
    }
    __syncthreads();
    float A = 1.0f, Hn = 0.0f;
    _Float16* ACp = AC + (size_t)(mBase + h * 64 + q * 16) * N2 + nBase + 2 * col;
#pragma unroll 4
    for (int rs = 0; rs < 16; ++rs) {
      f16x2 pp = *(const f16x2*)(smem + (q * 16 + rs) * 136 + 2 * col);
      float a, c;
      gate_ac((float)pp[0], (float)pp[1], alpha, a, c);
      f16x2 o;
      o[0] = (_Float16)a;
      o[1] = (_Float16)c;
      *(f16x2*)ACp = o;
      ACp += N2;
      A *= a;
      Hn = fmaf(a, Hn, c);
    }
    pAs[(h * 4 + q) * 65 + col] = A;
    pHs[(h * 4 + q) * 65 + col] = Hn;
    __syncthreads();
  }

  // combine 8x16-step partials -> 4x32-step aggregates (s-ascending pairs)
  if (t < 64) {
#pragma unroll
    for (int k = 0; k < 4; ++k) {
      float A0 = pAs[(2 * k) * 65 + t], H0 = pHs[(2 * k) * 65 + t];
      float A1 = pAs[(2 * k + 1) * 65 + t], H1 = pHs[(2 * k + 1) * 65 + t];
      const int ch = ((by & 15) << 2) + k;
      agg[((size_t)(b * 64 + ch)) * 2048 + (nBase >> 1) + t] =
          make_float2(A0 * A1, fmaf(A1, H0, H1));
    }
  }
}

__global__ __launch_bounds__(64) void scan_pass2(const float2* __restrict__ agg,
                                                 float* __restrict__ carry) {
  const int i = blockIdx.x * 64 + threadIdx.x;  // grid.x=32 -> 0..2047
  const int b = blockIdx.y;
  float h = 0.0f;
  for (int c8 = 0; c8 < 8; ++c8) {
    float2 aH[8];
#pragma unroll
    for (int u = 0; u < 8; ++u)
      aH[u] = agg[((size_t)(b * 64 + c8 * 8 + u)) * 2048 + i];
#pragma unroll
    for (int u = 0; u < 8; ++u) {
      carry[((size_t)(b * 64 + c8 * 8 + u)) * 2048 + i] = h;
      h = fmaf(aH[u].x, h, aH[u].y);
    }
  }
}

// Pure fma replay: h = a*h + c. 4 i's per thread, f16x8 loads + f32x4 stores,
// 2-deep ping-pong prefetch (static indexing), nontemporal (read/write-once).
__global__ __launch_bounds__(256) void scan_out(const _Float16* __restrict__ AC,
                                                const float* __restrict__ carry,
                                                float* __restrict__ out) {
  const int tt = blockIdx.x * 256 + threadIdx.x;  // 0..511 (4 i's per thread)
  const int i0 = tt * 4;
  const int ch = blockIdx.y;  // 0..63
  const int b = blockIdx.z;
  const float4 cr = ((const float4*)(carry + ((size_t)(b * 64 + ch)) * 2048))[tt];
  float h0 = cr.x, h1 = cr.y, h2 = cr.z, h3 = cr.w;
  const _Float16* row = AC + ((size_t)(b * 2048 + ch * 32)) * 4096 + i0 * 2;
  float* orow = out + ((size_t)(b * 2048 + ch * 32)) * 2048 + i0;

  f16x8 va[4], vb[4];
#pragma unroll
  for (int u = 0; u < 4; ++u)
    va[u] = __builtin_nontemporal_load((const f16x8*)(row + (size_t)u * 4096));

#pragma unroll
  for (int p = 0; p < 8; ++p) {
    if (p < 7) {
      const _Float16* nrow = row + (size_t)(p + 1) * 4 * 4096;
      f16x8* dst = (p & 1) ? va : vb;
#pragma unroll
      for (int u = 0; u < 4; ++u)
        dst[u] = __builtin_nontemporal_load((const f16x8*)(nrow + (size_t)u * 4096));
    }
    const f16x8* v = (p & 1) ? vb : va;
    float* op = orow + (size_t)p * 4 * 2048;
#pragma unroll
    for (int u = 0; u < 4; ++u) {
      h0 = fmaf((float)v[u][0], h0, (float)v[u][1]);
      h1 = fmaf((float)v[u][2], h1, (float)v[u][3]);
      h2 = fmaf((float)v[u][4], h2, (float)v[u][5]);
      h3 = fmaf((float)v[u][6], h3, (float)v[u][7]);
      f32x4 o;
      o[0] = h0;
      o[1] = h1;
      o[2] = h2;
      o[3] = h3;
      __builtin_nontemporal_store(o, (f32x4*)(op + (size_t)u * 2048));
    }
  }
}

extern "C" void kernel_launch(void* const* d_in, const int* in_sizes, int n_in,
                              void* d_out, int out_size, void* d_ws, size_t ws_size,
                              hipStream_t stream) {
  const float* x = (const float*)d_in[0];
  const float* Wa = (const float*)d_in[1];
  const float* ba = (const float*)d_in[2];
  const float* Wi = (const float*)d_in[3];
  const float* bi = (const float*)d_in[4];
  const float* gate = (const float*)d_in[5];
  float* out = (float*)d_out;

  char* ws = (char*)d_ws;
  _Float16* xh = (_Float16*)ws;               // 16 MiB
  _Float16* wh = (_Float16*)(ws + 16777216);  // 4 MiB (interleaved Wa/Wi)
  const size_t MN2 = (size_t)16384 * 4096;
  _Float16* AC = (_Float16*)(ws + 20971520);  // 128 MiB fp16 (a,c) interleaved
  float2* agg = (float2*)(ws + 20971520 + MN2 * 2);            // 8 MiB
  float* carry = (float*)(ws + 20971520 + MN2 * 2 + 8388608);  // 4 MiB

  cvt_all<<<10240, 256, 0, stream>>>(x, Wa, Wi, xh, wh);
  gemm_gate<<<dim3(32, 128), 256, 0, stream>>>(xh, wh, ba, bi, gate, AC, agg);
  scan_pass2<<<dim3(32, 8), 64, 0, stream>>>(agg, carry);
  scan_out<<<dim3(2, 64, 8), 256, 0, stream>>>(AC, carry, out);
}

// Round 9
// 331.373 us; speedup vs baseline: 1.0274x; 1.0274x over previous
//
#include <hip/hip_runtime.h>

// GatedRecurrentCell: pa/pi = x@W^T + b (fp16 MFMA) with gates FUSED into the
// GEMM epilogue; (a,c) stored fp16; chunked linear scan (64 chunks x 32 steps).
// Shapes: B=8 S=2048 D=512 I=2048. M=B*S=16384, N2=2*I=4096, K=D=512.
// R9: 256x256 TILE (BK=32, 8 waves, 512 thr). Evidence: 5 variants all pin
// staging traffic 1.02GB at ~6.9 TB/s (VMEM-path ceiling) -> TRAFFIC-bound.
// Traffic = 16MB*(N2/BN) + 4MB*(M/BM): 256^2 halves it to 512MB. Same proven
// 2-phase loop (R6/R8-verified), same XOR swizzle (involution holds: wm/wn/128
// offsets all =0 mod 4 in (row>>1)&3). Epilogue -> 4 rounds of 64 m-rows;
// pAs/pHs/C-stage aliased into the 64KB staging LDS (post-barrier reuse).
// XCD remap reverted (R8: FETCH 2x worse, dur ~same -> not HBM-bound).
// ws: [0,16Mi) x_f16 | [16,20Mi) W_f16 | [20Mi,+128Mi) AC f16 | +8Mi agg | +4Mi carry

#define LOG2_3 1.5849625007211562f

typedef _Float16 f16x8 __attribute__((ext_vector_type(8)));
typedef _Float16 f16x4 __attribute__((ext_vector_type(4)));
typedef _Float16 f16x2 __attribute__((ext_vector_type(2)));
typedef float f32x4 __attribute__((ext_vector_type(4)));

__device__ __forceinline__ float sigmoid_fast(float v) {
  return __fdividef(1.0f, 1.0f + __expf(-v));
}

__device__ __forceinline__ void async_copy16(void* lds, const void* gp) {
  __builtin_amdgcn_global_load_lds((__attribute__((address_space(1))) void*)gp,
                                   (__attribute__((address_space(3))) void*)lds,
                                   16, 0, 0);
}

// x -> xh (plain). Wa/Wi -> wh with row interleave: wh row 2i = Wa_i, 2i+1 = Wi_i.
__global__ __launch_bounds__(256) void cvt_all(const float* __restrict__ x,
                                               const float* __restrict__ Wa,
                                               const float* __restrict__ Wi,
                                               _Float16* __restrict__ xh,
                                               _Float16* __restrict__ wh) {
  int idx = blockIdx.x * 256 + threadIdx.x;
  const float* src;
  _Float16* dst;
  int off, doff;
  if (idx < 2097152) {
    src = x; dst = xh; off = idx; doff = idx;
  } else if (idx < 2097152 + 262144) {
    src = Wa; dst = wh; off = idx - 2097152;
    doff = off + ((off >> 7) << 7);          // (2i)*128 + k4
  } else {
    src = Wi; dst = wh; off = idx - 2359296;
    doff = off + ((off >> 7) << 7) + 128;    // (2i+1)*128 + k4
  }
  float4 v = ((const float4*)src)[off];
  f16x4 h;
  h[0] = (_Float16)v.x;
  h[1] = (_Float16)v.y;
  h[2] = (_Float16)v.z;
  h[3] = (_Float16)v.w;
  ((f16x4*)dst)[doff] = h;
}

__device__ __forceinline__ void gate_ac(float pa, float pi, float alpha, float& a, float& c) {
  float rg = sigmoid_fast(pa);
  a = alpha * exp2f(-LOG2_3 * rg);
  float ig = sigmoid_fast(pi);
  float m = fmaxf(1.0f - a * a, 1e-8f);
  c = (m * __frsqrt_rn(m)) * (ig * pi);  // sqrt(m) = m * rsqrt(m)
}

// GEMM 256x256 tile + fused gate epilogue. 8 waves: wm=(w&1)*128, wn=(w>>1)*64;
// per-wave 128x64 out = acc[8][4] f32x4.
// LDS (64 KiB): buf k = smem + k*16384 f16; within buf: A rows 0-255 at
// [0,8192) (row*32), B rows 0-255 at [8192,16384). Staging (512 thr, 4 insts):
// r=t>>2 (0..127), p=t&3, dest byte = t*16 (linear, required by gload_lds);
// rows r and r+128 per operand. Swizzle: slot s at row r holds s^((r>>1)&3);
// source pre-swizzled lsw = p^((r>>1)&3) (r+128 gives same f), read xq =
// quad^((lrow>>1)&3) (wm/wn/i*16 all =0 mod 4 in f).
// Epilogue: 4 rounds of 64 m-rows; C-stage 64x264 f16 at smem[0,16896);
// pAs/pHs 16x132 f32 at smem+18432 (byte 36864..53760) - post-barrier alias.
__global__ __launch_bounds__(512) void gemm_gate(const _Float16* __restrict__ Ah,
                                                 const _Float16* __restrict__ Wh,
                                                 const float* __restrict__ ba,
                                                 const float* __restrict__ bi,
                                                 const float* __restrict__ gate,
                                                 _Float16* __restrict__ AC,
                                                 float2* __restrict__ agg) {
  constexpr int K = 512;
  constexpr int N2 = 4096;
  __shared__ __align__(16) _Float16 smem[32768];  // 64 KiB
  const int t = threadIdx.x;
  const int bx = blockIdx.x;  // 0..15 (n)
  const int by = blockIdx.y;  // 0..63 (m)
  const int mBase = by * 256;
  const int nBase = bx * 256;
  const int r = t >> 2;                      // staged row 0..127 (+128 for 2nd)
  const int p = t & 3;                       // physical 16B slot
  const int lsw = p ^ ((r >> 1) & 3);        // pre-swizzled source slot
  const _Float16* gA0 = Ah + (size_t)(mBase + r) * K + lsw * 8;
  const _Float16* gB0 = Wh + (size_t)(nBase + r) * K + lsw * 8;
  const int ldst = r * 32 + p * 8;           // byte off == t*16 (linear)

  const int lane = t & 63;
  const int wave = t >> 6;                   // 0..7
  const int wm = (wave & 1) * 128;
  const int wn = (wave >> 1) * 64;
  const int lrow = lane & 15;
  const int quad = lane >> 4;
  const int xq = quad ^ ((lrow >> 1) & 3);   // read-side swizzle

  f32x4 acc[8][4];
#pragma unroll
  for (int i = 0; i < 8; ++i)
#pragma unroll
    for (int j = 0; j < 4; ++j)
      acc[i][j] = (f32x4)0.0f;

  _Float16* b0 = smem;
  _Float16* b1 = smem + 16384;

  auto STAGE = [&](int tt, _Float16* bb) {
    const int ko = tt * 32;
    async_copy16(bb + ldst, gA0 + ko);                            // A rows 0-127
    async_copy16(bb + 4096 + ldst, gA0 + (size_t)128 * K + ko);   // A rows 128-255
    async_copy16(bb + 8192 + ldst, gB0 + ko);                     // B rows 0-127
    async_copy16(bb + 12288 + ldst, gB0 + (size_t)128 * K + ko);  // B rows 128-255
  };

  STAGE(0, b0);
  __syncthreads();

#pragma unroll
  for (int kt = 0; kt < 16; ++kt) {
    _Float16* cur = (kt & 1) ? b1 : b0;
    _Float16* nxt = (kt & 1) ? b0 : b1;
    if (kt < 15) STAGE(kt + 1, nxt);  // issue BEFORE compute; lands by next barrier
    f16x8 af[8], bf[4];
#pragma unroll
    for (int i = 0; i < 8; ++i)
      af[i] = *(const f16x8*)(cur + (wm + i * 16 + lrow) * 32 + xq * 8);
#pragma unroll
    for (int j = 0; j < 4; ++j)
      bf[j] = *(const f16x8*)(cur + 8192 + (wn + j * 16 + lrow) * 32 + xq * 8);
#pragma unroll
    for (int i = 0; i < 8; ++i)
#pragma unroll
      for (int j = 0; j < 4; ++j)
        acc[i][j] = __builtin_amdgcn_mfma_f32_16x16x32_f16(af[i], bf[j], acc[i][j], 0, 0, 0);
    __syncthreads();  // single barrier/K-step: drains stage + reads, publishes nxt
  }

  // bias: col n even -> ba[n/2] (pa), odd -> bi[n/2] (pi)
  float bias[4];
#pragma unroll
  for (int j = 0; j < 4; ++j) {
    const int n = nBase + wn + j * 16 + lrow;
    bias[j] = (n & 1) ? bi[n >> 1] : ba[n >> 1];
  }

  _Float16* cst = smem;                  // 64 x 264 f16 C-stage
  float* pAs = (float*)(smem + 18432);   // 16 x 132 f32
  float* pHs = pAs + 16 * 132;

  // gate-phase roles: col = i-lane 0..127, q = s-quarter (16 rows each)
  const int col = t & 127;
  const int q = t >> 7;
  const float alpha = sigmoid_fast(gate[(nBase >> 1) + col]);
  const int b = by >> 3;  // 8 m-tiles (256 rows) per batch

  // 4 rounds of 64 m-rows. C/D frag: col=lane&15, row=quad*4+reg (m89).
  // Round h rows [h*64,(h+1)*64): written by waves wm==(h>>1)*128,
  // frags i in [(h&1)*4, (h&1)*4+4).
#pragma unroll
  for (int h = 0; h < 4; ++h) {
    if (wm == (h >> 1) * 128) {
      const int i0f = (h & 1) * 4;
#pragma unroll
      for (int ii = 0; ii < 4; ++ii)
#pragma unroll
        for (int j = 0; j < 4; ++j)
#pragma unroll
          for (int rr = 0; rr < 4; ++rr)
            cst[(ii * 16 + quad * 4 + rr) * 264 + wn + j * 16 + lrow] =
                (_Float16)(acc[i0f + ii][j][rr] + bias[j]);
    }
    __syncthreads();
    float A = 1.0f, Hn = 0.0f;
    _Float16* ACp = AC + (size_t)(mBase + h * 64 + q * 16) * N2 + nBase + 2 * col;
#pragma unroll 4
    for (int rs = 0; rs < 16; ++rs) {
      f16x2 pp = *(const f16x2*)(cst + (q * 16 + rs) * 264 + 2 * col);
      float a, c;
      gate_ac((float)pp[0], (float)pp[1], alpha, a, c);
      f16x2 o;
      o[0] = (_Float16)a;
      o[1] = (_Float16)c;
      *(f16x2*)ACp = o;
      ACp += N2;
      A *= a;
      Hn = fmaf(a, Hn, c);
    }
    pAs[(h * 4 + q) * 132 + col] = A;
    pHs[(h * 4 + q) * 132 + col] = Hn;
    __syncthreads();
  }

  // combine 16x16-step strips -> 8x32-step chunk aggregates (s-ascending pairs)
  if (t < 128) {
#pragma unroll
    for (int k = 0; k < 8; ++k) {
      float A0 = pAs[(2 * k) * 132 + t], H0 = pHs[(2 * k) * 132 + t];
      float A1 = pAs[(2 * k + 1) * 132 + t], H1 = pHs[(2 * k + 1) * 132 + t];
      const int ch = ((by & 7) << 3) + k;
      agg[((size_t)(b * 64 + ch)) * 2048 + (nBase >> 1) + t] =
          make_float2(A0 * A1, fmaf(A1, H0, H1));
    }
  }
}

__global__ __launch_bounds__(64) void scan_pass2(const float2* __restrict__ agg,
                                                 float* __restrict__ carry) {
  const int i = blockIdx.x * 64 + threadIdx.x;  // grid.x=32 -> 0..2047
  const int b = blockIdx.y;
  float h = 0.0f;
  for (int c8 = 0; c8 < 8; ++c8) {
    float2 aH[8];
#pragma unroll
    for (int u = 0; u < 8; ++u)
      aH[u] = agg[((size_t)(b * 64 + c8 * 8 + u)) * 2048 + i];
#pragma unroll
    for (int u = 0; u < 8; ++u) {
      carry[((size_t)(b * 64 + c8 * 8 + u)) * 2048 + i] = h;
      h = fmaf(aH[u].x, h, aH[u].y);
    }
  }
}

// Pure fma replay: h = a*h + c. 4 i's per thread, f16x8 loads + f32x4 stores,
// 2-deep ping-pong prefetch (static indexing), nontemporal (read/write-once).
__global__ __launch_bounds__(256) void scan_out(const _Float16* __restrict__ AC,
                                                const float* __restrict__ carry,
                                                float* __restrict__ out) {
  const int tt = blockIdx.x * 256 + threadIdx.x;  // 0..511 (4 i's per thread)
  const int i0 = tt * 4;
  const int ch = blockIdx.y;  // 0..63
  const int b = blockIdx.z;
  const float4 cr = ((const float4*)(carry + ((size_t)(b * 64 + ch)) * 2048))[tt];
  float h0 = cr.x, h1 = cr.y, h2 = cr.z, h3 = cr.w;
  const _Float16* row = AC + ((size_t)(b * 2048 + ch * 32)) * 4096 + i0 * 2;
  float* orow = out + ((size_t)(b * 2048 + ch * 32)) * 2048 + i0;

  f16x8 va[4], vb[4];
#pragma unroll
  for (int u = 0; u < 4; ++u)
    va[u] = __builtin_nontemporal_load((const f16x8*)(row + (size_t)u * 4096));

#pragma unroll
  for (int p = 0; p < 8; ++p) {
    if (p < 7) {
      const _Float16* nrow = row + (size_t)(p + 1) * 4 * 4096;
      f16x8* dst = (p & 1) ? va : vb;
#pragma unroll
      for (int u = 0; u < 4; ++u)
        dst[u] = __builtin_nontemporal_load((const f16x8*)(nrow + (size_t)u * 4096));
    }
    const f16x8* v = (p & 1) ? vb : va;
    float* op = orow + (size_t)p * 4 * 2048;
#pragma unroll
    for (int u = 0; u < 4; ++u) {
      h0 = fmaf((float)v[u][0], h0, (float)v[u][1]);
      h1 = fmaf((float)v[u][2], h1, (float)v[u][3]);
      h2 = fmaf((float)v[u][4], h2, (float)v[u][5]);
      h3 = fmaf((float)v[u][6], h3, (float)v[u][7]);
      f32x4 o;
      o[0] = h0;
      o[1] = h1;
      o[2] = h2;
      o[3] = h3;
      __builtin_nontemporal_store(o, (f32x4*)(op + (size_t)u * 2048));
    }
  }
}

extern "C" void kernel_launch(void* const* d_in, const int* in_sizes, int n_in,
                              void* d_out, int out_size, void* d_ws, size_t ws_size,
                              hipStream_t stream) {
  const float* x = (const float*)d_in[0];
  const float* Wa = (const float*)d_in[1];
  const float* ba = (const float*)d_in[2];
  const float* Wi = (const float*)d_in[3];
  const float* bi = (const float*)d_in[4];
  const float* gate = (const float*)d_in[5];
  float* out = (float*)d_out;

  char* ws = (char*)d_ws;
  _Float16* xh = (_Float16*)ws;               // 16 MiB
  _Float16* wh = (_Float16*)(ws + 16777216);  // 4 MiB (interleaved Wa/Wi)
  const size_t MN2 = (size_t)16384 * 4096;
  _Float16* AC = (_Float16*)(ws + 20971520);  // 128 MiB fp16 (a,c) interleaved
  float2* agg = (float2*)(ws + 20971520 + MN2 * 2);            // 8 MiB
  float* carry = (float*)(ws + 20971520 + MN2 * 2 + 8388608);  // 4 MiB

  cvt_all<<<10240, 256, 0, stream>>>(x, Wa, Wi, xh, wh);
  gemm_gate<<<dim3(16, 64), 512, 0, stream>>>(xh, wh, ba, bi, gate, AC, agg);
  scan_pass2<<<dim3(32, 8), 64, 0, stream>>>(agg, carry);
  scan_out<<<dim3(2, 64, 8), 256, 0, stream>>>(AC, carry, out);
}